// Round 1
// baseline (931.695 us; speedup 1.0000x reference)
//
#include <hip/hip_runtime.h>
#include <hip/hip_bf16.h>

#define NEG_INF (-__builtin_inff())

// ---------------- wave reduce helpers ----------------
__device__ inline float wave_sum64(float v) {
#pragma unroll
  for (int m = 32; m >= 1; m >>= 1) v += __shfl_xor(v, m, 64);
  return v;
}
__device__ inline float wave_max64(float v) {
#pragma unroll
  for (int m = 32; m >= 1; m >>= 1) v = fmaxf(v, __shfl_xor(v, m, 64));
  return v;
}

// ---------------- graph boundary kernel ----------------
// batch is sorted ascending in [0,G). starts[g] = first i with batch[i] >= g; starts[G] = N.
__global__ void starts_kernel(const int* __restrict__ batch, int* __restrict__ starts,
                              int N, int G) {
  int i = blockIdx.x * blockDim.x + threadIdx.x;
  if (i >= N) return;
  int b = batch[i];
  if (i == 0) {
    for (int g = 0; g <= b; ++g) starts[g] = 0;
  } else {
    int bp = batch[i - 1];
    for (int g = bp + 1; g <= b; ++g) starts[g] = i;
  }
  if (i == N - 1) {
    for (int g = b + 1; g <= G; ++g) starts[g] = N;
  }
}

// ---------------- generic f32 GEMM: C = act(A[M,K] @ B[K,N] + bias) ----------------
// 64x64 tile, 256 threads, 4x4 micro-tile, BK=16. M % 64 == 0, K % 16 == 0 required.
// N arbitrary (column-guarded).
template <int ACT>  // 0 = none, 1 = relu
__global__ __launch_bounds__(256) void gemm_kernel(
    const float* __restrict__ A, const float* __restrict__ B,
    const float* __restrict__ bias, float* __restrict__ C,
    int M, int N, int K) {
  __shared__ float As[64][17];  // [m][k], padded to kill bank conflicts on As[m][k] reads
  __shared__ float Bs[16][64];  // [k][n]

  const int t = threadIdx.x;
  const int bm = blockIdx.y, bn = blockIdx.x;
  const int tx = t & 15, ty = t >> 4;

  const int arow = t >> 2;          // 0..63
  const int acol = (t & 3) << 2;    // 0,4,8,12
  const int brow = t >> 4;          // 0..15
  const int bcol = (t & 15) << 2;   // 0..60
  const int gcol = bn * 64 + bcol;

  float acc[4][4];
#pragma unroll
  for (int i = 0; i < 4; ++i)
#pragma unroll
    for (int j = 0; j < 4; ++j) acc[i][j] = 0.f;

  const float* Aptr = A + (size_t)(bm * 64 + arow) * K + acol;

  for (int k0 = 0; k0 < K; k0 += 16) {
    // stage A (64x16)
    float4 av = *(const float4*)(Aptr + k0);
    As[arow][acol + 0] = av.x;
    As[arow][acol + 1] = av.y;
    As[arow][acol + 2] = av.z;
    As[arow][acol + 3] = av.w;
    // stage B (16x64), column-guarded
    float4 bv = make_float4(0.f, 0.f, 0.f, 0.f);
    if (gcol + 3 < N) {
      bv = *(const float4*)(B + (size_t)(k0 + brow) * N + gcol);
    } else {
      if (gcol + 0 < N) bv.x = B[(size_t)(k0 + brow) * N + gcol + 0];
      if (gcol + 1 < N) bv.y = B[(size_t)(k0 + brow) * N + gcol + 1];
      if (gcol + 2 < N) bv.z = B[(size_t)(k0 + brow) * N + gcol + 2];
    }
    *(float4*)&Bs[brow][bcol] = bv;
    __syncthreads();

#pragma unroll
    for (int k = 0; k < 16; ++k) {
      float a0 = As[ty * 4 + 0][k];
      float a1 = As[ty * 4 + 1][k];
      float a2 = As[ty * 4 + 2][k];
      float a3 = As[ty * 4 + 3][k];
      float4 b4 = *(const float4*)&Bs[k][tx * 4];
      acc[0][0] += a0 * b4.x; acc[0][1] += a0 * b4.y; acc[0][2] += a0 * b4.z; acc[0][3] += a0 * b4.w;
      acc[1][0] += a1 * b4.x; acc[1][1] += a1 * b4.y; acc[1][2] += a1 * b4.z; acc[1][3] += a1 * b4.w;
      acc[2][0] += a2 * b4.x; acc[2][1] += a2 * b4.y; acc[2][2] += a2 * b4.z; acc[2][3] += a2 * b4.w;
      acc[3][0] += a3 * b4.x; acc[3][1] += a3 * b4.y; acc[3][2] += a3 * b4.z; acc[3][3] += a3 * b4.w;
    }
    __syncthreads();
  }

  const int crow = bm * 64 + ty * 4;
  const int ccol = bn * 64 + tx * 4;
#pragma unroll
  for (int i = 0; i < 4; ++i) {
#pragma unroll
    for (int j = 0; j < 4; ++j) {
      int c = ccol + j;
      if (c < N) {
        float v = acc[i][j] + bias[c];
        if (ACT == 1) v = fmaxf(v, 0.f);
        C[(size_t)(crow + i) * N + c] = v;
      }
    }
  }
}

// ---------------- block-diagonal flash attention ----------------
// qkv: [N, 768] rows = [q(256) | k(256) | v(256)], head h uses cols h*32..h*32+31.
// One wave (64 threads) per (node i, head h). Online softmax over the node's graph.
__global__ __launch_bounds__(64) void attn_kernel(
    const float* __restrict__ qkv, const int* __restrict__ starts,
    const int* __restrict__ batch, float* __restrict__ out) {
  __shared__ float red[64][32];
  const int i = blockIdx.x >> 3;
  const int h = blockIdx.x & 7;
  const int lane = threadIdx.x;
  const int g = batch[i];
  const int js = starts[g], je = starts[g + 1];

  const float* qp = qkv + (size_t)i * 768 + h * 32;
  float q[32];
#pragma unroll
  for (int d4 = 0; d4 < 8; ++d4) {
    float4 v = *(const float4*)(qp + d4 * 4);
    q[d4 * 4 + 0] = v.x; q[d4 * 4 + 1] = v.y; q[d4 * 4 + 2] = v.z; q[d4 * 4 + 3] = v.w;
  }

  float m = NEG_INF, lsum = 0.f;
  float acc[32];
#pragma unroll
  for (int d = 0; d < 32; ++d) acc[d] = 0.f;
  const float scale = 0.17677669529663687f;  // 1/sqrt(32)

  for (int j = js + lane; j < je; j += 64) {
    const float* kp = qkv + (size_t)j * 768 + 256 + h * 32;
    float s = 0.f;
#pragma unroll
    for (int d4 = 0; d4 < 8; ++d4) {
      float4 kv = *(const float4*)(kp + d4 * 4);
      s += q[d4 * 4 + 0] * kv.x + q[d4 * 4 + 1] * kv.y +
           q[d4 * 4 + 2] * kv.z + q[d4 * 4 + 3] * kv.w;
    }
    s *= scale;
    float mo = m;
    m = fmaxf(m, s);
    float corr = __expf(mo - m);  // mo=-inf on first iter -> 0
    float p = __expf(s - m);
    lsum = lsum * corr + p;
    const float* vp = kp + 256;
#pragma unroll
    for (int d4 = 0; d4 < 8; ++d4) {
      float4 vv = *(const float4*)(vp + d4 * 4);
      acc[d4 * 4 + 0] = acc[d4 * 4 + 0] * corr + p * vv.x;
      acc[d4 * 4 + 1] = acc[d4 * 4 + 1] * corr + p * vv.y;
      acc[d4 * 4 + 2] = acc[d4 * 4 + 2] * corr + p * vv.z;
      acc[d4 * 4 + 3] = acc[d4 * 4 + 3] * corr + p * vv.w;
    }
  }

  float mw = wave_max64(m);
  float corr = (m == NEG_INF) ? 0.f : __expf(m - mw);
  lsum *= corr;
  lsum = wave_sum64(lsum);
#pragma unroll
  for (int d = 0; d < 32; ++d) red[lane][d] = acc[d] * corr;
  __syncthreads();
  if (lane < 32) {
    float s = 0.f;
#pragma unroll
    for (int l = 0; l < 64; ++l) s += red[l][lane];
    out[(size_t)i * 256 + h * 32 + lane] = s / lsum;
  }
}

// ---------------- fused residual + LayerNorm (D=256) ----------------
// out[row,:] = LN(base[row,:] + delta[row,:]) * s + b. One wave per row, 4 rows/block.
__global__ __launch_bounds__(256) void ln_kernel(
    const float* __restrict__ base, const float* __restrict__ delta,
    const float* __restrict__ s, const float* __restrict__ b,
    float* __restrict__ out) {
  const int row = blockIdx.x * 4 + (threadIdx.x >> 6);
  const int lane = threadIdx.x & 63;
  const float4 xa = *(const float4*)(base + (size_t)row * 256 + lane * 4);
  const float4 xb = *(const float4*)(delta + (size_t)row * 256 + lane * 4);
  float4 v = make_float4(xa.x + xb.x, xa.y + xb.y, xa.z + xb.z, xa.w + xb.w);
  float sum = v.x + v.y + v.z + v.w;
  sum = wave_sum64(sum);
  const float mean = sum * (1.f / 256.f);
  float4 d = make_float4(v.x - mean, v.y - mean, v.z - mean, v.w - mean);
  float sq = d.x * d.x + d.y * d.y + d.z * d.z + d.w * d.w;
  sq = wave_sum64(sq);
  const float rs = rsqrtf(sq * (1.f / 256.f) + 1e-5f);
  const float4 sv = *(const float4*)(s + lane * 4);
  const float4 bv = *(const float4*)(b + lane * 4);
  float4 o = make_float4(d.x * rs * sv.x + bv.x, d.y * rs * sv.y + bv.y,
                         d.z * rs * sv.z + bv.z, d.w * rs * sv.w + bv.w);
  *(float4*)(out + (size_t)row * 256 + lane * 4) = o;
}

// ---------------- lat normalization (rows of 32) ----------------
__global__ __launch_bounds__(256) void latnorm_kernel(float* __restrict__ lat) {
  const int idx = blockIdx.x * 256 + threadIdx.x;
  const int row = idx >> 5;
  const int c = idx & 31;
  float v = lat[(size_t)row * 32 + c];
  float sq = v * v;
#pragma unroll
  for (int m = 16; m >= 1; m >>= 1) sq += __shfl_xor(sq, m, 32);
  const float norm = fmaxf(sqrtf(sq), 1e-12f);
  lat[(size_t)row * 32 + c] = v / norm * 5.656854249492381f;  // sqrt(32)
}

// ---------------- beta head: sigmoid(bh[row,:] @ w + b) ----------------
__global__ __launch_bounds__(256) void beta_kernel(
    const float* __restrict__ bh, const float* __restrict__ w,
    const float* __restrict__ b2b, float* __restrict__ beta) {
  const int row = blockIdx.x * 4 + (threadIdx.x >> 6);
  const int lane = threadIdx.x & 63;
  float p = bh[(size_t)row * 128 + lane] * w[lane] +
            bh[(size_t)row * 128 + 64 + lane] * w[64 + lane];
  p = wave_sum64(p);
  if (lane == 0) {
    float x = p + b2b[0];
    float sgm = 1.f / (1.f + __expf(-x));
    sgm = fminf(fmaxf(sgm, 1e-6f), 1.f - 1e-6f);
    beta[row] = sgm;
  }
}

// ---------------- launch ----------------
extern "C" void kernel_launch(void* const* d_in, const int* in_sizes, int n_in,
                              void* d_out, int out_size, void* d_ws, size_t ws_size,
                              hipStream_t stream) {
  const int N = 2048, G = 16, D = 256, FF = 1024, L = 4;

  const float* x     = (const float*)d_in[0];
  // d_in[1] = coords (unused)
  const int*   batch = (const int*)d_in[2];
  const float* Wi    = (const float*)d_in[3];
  const float* bi    = (const float*)d_in[4];
  const float* qkv_w = (const float*)d_in[5];
  const float* qkv_b = (const float*)d_in[6];
  const float* out_w = (const float*)d_in[7];
  const float* out_b = (const float*)d_in[8];
  const float* ff1_w = (const float*)d_in[9];
  const float* ff1_b = (const float*)d_in[10];
  const float* ff2_w = (const float*)d_in[11];
  const float* ff2_b = (const float*)d_in[12];
  const float* ln1_s = (const float*)d_in[13];
  const float* ln1_b = (const float*)d_in[14];
  const float* ln2_s = (const float*)d_in[15];
  const float* ln2_b = (const float*)d_in[16];
  const float* lat_w = (const float*)d_in[17];
  const float* lat_b = (const float*)d_in[18];
  const float* b1_w  = (const float*)d_in[19];
  const float* b1_b  = (const float*)d_in[20];
  const float* b2_w  = (const float*)d_in[21];
  const float* b2_b  = (const float*)d_in[22];

  float* ws = (float*)d_ws;
  float* h       = ws;                      // N*D      = 524288
  float* qkv     = h + (size_t)N * D;       // N*3D     = 1572864
  float* attnout = qkv + (size_t)N * 3 * D; // N*D
  float* tmp     = attnout + (size_t)N * D; // N*D
  float* ffbuf   = tmp + (size_t)N * D;     // N*FF     = 2097152
  float* bh      = ffbuf + (size_t)N * FF;  // N*128
  int*   starts  = (int*)(bh + (size_t)N * 128);  // G+1 ints

  float* beta_out = (float*)d_out;
  float* lat_out  = beta_out + N;

  starts_kernel<<<(N + 255) / 256, 256, 0, stream>>>(batch, starts, N, G);

  // h = x @ Wi + bi   [2048,16]@[16,256]
  gemm_kernel<0><<<dim3(D / 64, N / 64), 256, 0, stream>>>(x, Wi, bi, h, N, D, 16);

  for (int l = 0; l < L; ++l) {
    // qkv = h @ qkv_w[l] + qkv_b[l]
    gemm_kernel<0><<<dim3(3 * D / 64, N / 64), 256, 0, stream>>>(
        h, qkv_w + (size_t)l * D * 3 * D, qkv_b + (size_t)l * 3 * D, qkv, N, 3 * D, D);
    // block-diagonal attention
    attn_kernel<<<N * 8, 64, 0, stream>>>(qkv, starts, batch, attnout);
    // o = attnout @ out_w[l] + out_b[l]
    gemm_kernel<0><<<dim3(D / 64, N / 64), 256, 0, stream>>>(
        attnout, out_w + (size_t)l * D * D, out_b + (size_t)l * D, tmp, N, D, D);
    // h = LN(h + o)
    ln_kernel<<<N / 4, 256, 0, stream>>>(h, tmp, ln1_s + (size_t)l * D, ln1_b + (size_t)l * D, h);
    // ff = relu(h @ ff1_w[l] + ff1_b[l])
    gemm_kernel<1><<<dim3(FF / 64, N / 64), 256, 0, stream>>>(
        h, ff1_w + (size_t)l * D * FF, ff1_b + (size_t)l * FF, ffbuf, N, FF, D);
    // f = ff @ ff2_w[l] + ff2_b[l]
    gemm_kernel<0><<<dim3(D / 64, N / 64), 256, 0, stream>>>(
        ffbuf, ff2_w + (size_t)l * FF * D, ff2_b + (size_t)l * D, tmp, N, D, FF);
    // h = LN(h + f)
    ln_kernel<<<N / 4, 256, 0, stream>>>(h, tmp, ln2_s + (size_t)l * D, ln2_b + (size_t)l * D, h);
  }

  // lat = h @ lat_w + lat_b  -> normalize in place in d_out
  gemm_kernel<0><<<dim3(1, N / 64), 256, 0, stream>>>(h, lat_w, lat_b, lat_out, N, 32, D);
  latnorm_kernel<<<(N * 32) / 256, 256, 0, stream>>>(lat_out);

  // bh = relu(h @ b1_w + b1_b); beta = clip(sigmoid(bh @ b2_w + b2_b))
  gemm_kernel<1><<<dim3(2, N / 64), 256, 0, stream>>>(h, b1_w, b1_b, bh, N, 128, D);
  beta_kernel<<<N / 4, 256, 0, stream>>>(bh, b2_w, b2_b, beta_out);
}

// Round 2
// 506.239 us; speedup vs baseline: 1.8404x; 1.8404x over previous
//
#include <hip/hip_runtime.h>
#include <hip/hip_bf16.h>

#define NEG_INF (-__builtin_inff())

typedef __attribute__((ext_vector_type(8))) short bf16x8;
typedef __attribute__((ext_vector_type(4))) float f32x4;

// ---------------- helpers ----------------
__device__ inline float wave_sum64(float v) {
#pragma unroll
  for (int m = 32; m >= 1; m >>= 1) v += __shfl_xor(v, m, 64);
  return v;
}
__device__ inline float wave_max64(float v) {
#pragma unroll
  for (int m = 32; m >= 1; m >>= 1) v = fmaxf(v, __shfl_xor(v, m, 64));
  return v;
}
__device__ inline ushort f2bf(float f) {  // RNE float->bf16
  uint u = __float_as_uint(f);
  return (ushort)((u + 0x7FFFu + ((u >> 16) & 1u)) >> 16);
}

// ---------------- graph boundary kernel ----------------
__global__ void starts_kernel(const int* __restrict__ batch, int* __restrict__ starts,
                              int N, int G) {
  int i = blockIdx.x * blockDim.x + threadIdx.x;
  if (i >= N) return;
  int b = batch[i];
  if (i == 0) {
    for (int g = 0; g <= b; ++g) starts[g] = 0;
  } else {
    int bp = batch[i - 1];
    for (int g = bp + 1; g <= b; ++g) starts[g] = i;
  }
  if (i == N - 1) {
    for (int g = b + 1; g <= G; ++g) starts[g] = N;
  }
}

// ---------------- weight pack: f32 [K][N] -> bf16 [N][K] (B^T), all weights ----------------
// 32x32 tiles, 256 threads. Tile ranges: qkv[0,768) out[768,1024) ff1[1024,2048)
// ff2[2048,3072) b1[3072,3104) lat[3104,3112)
__global__ __launch_bounds__(256) void pack_weights(
    const float* __restrict__ qkv_w, const float* __restrict__ out_w,
    const float* __restrict__ ff1_w, const float* __restrict__ ff2_w,
    const float* __restrict__ b1_w, const float* __restrict__ lat_w,
    short* __restrict__ qkv_t, short* __restrict__ out_t,
    short* __restrict__ ff1_t, short* __restrict__ ff2_t,
    short* __restrict__ b1_t, short* __restrict__ lat_t) {
  int t = blockIdx.x;
  const float* src;
  short* dst;
  int Kd, Nd, rem;
  if (t < 768) {
    int l = t / 192; rem = t % 192; Kd = 256; Nd = 768;
    src = qkv_w + (size_t)l * Kd * Nd; dst = qkv_t + (size_t)l * Nd * Kd;
  } else if (t < 1024) {
    t -= 768; int l = t / 64; rem = t % 64; Kd = 256; Nd = 256;
    src = out_w + (size_t)l * Kd * Nd; dst = out_t + (size_t)l * Nd * Kd;
  } else if (t < 2048) {
    t -= 1024; int l = t / 256; rem = t % 256; Kd = 256; Nd = 1024;
    src = ff1_w + (size_t)l * Kd * Nd; dst = ff1_t + (size_t)l * Nd * Kd;
  } else if (t < 3072) {
    t -= 2048; int l = t / 256; rem = t % 256; Kd = 1024; Nd = 256;
    src = ff2_w + (size_t)l * Kd * Nd; dst = ff2_t + (size_t)l * Nd * Kd;
  } else if (t < 3104) {
    rem = t - 3072; Kd = 256; Nd = 128; src = b1_w; dst = b1_t;
  } else {
    rem = t - 3104; Kd = 256; Nd = 32; src = lat_w; dst = lat_t;
  }
  const int ntn = Nd / 32;
  const int kt = rem / ntn, nt = rem % ntn;

  __shared__ float tile[32][33];
  const int tx = threadIdx.x & 31, ty = threadIdx.x >> 5;
#pragma unroll
  for (int r = 0; r < 4; ++r) {
    int k = kt * 32 + ty + r * 8;
    tile[ty + r * 8][tx] = src[(size_t)k * Nd + nt * 32 + tx];
  }
  __syncthreads();
#pragma unroll
  for (int r = 0; r < 4; ++r) {
    int n = nt * 32 + ty + r * 8;
    dst[(size_t)n * Kd + kt * 32 + tx] = (short)f2bf(tile[tx][ty + r * 8]);
  }
}

// ---------------- input projection: h = x @ Wi + bi  (K=16, D=256) ----------------
__global__ __launch_bounds__(256) void inproj_kernel(
    const float* __restrict__ x, const float* __restrict__ Wi,
    const float* __restrict__ bi, float* __restrict__ h) {
  __shared__ float xs[16];
  const int i = blockIdx.x, j = threadIdx.x;
  if (j < 16) xs[j] = x[(size_t)i * 16 + j];
  __syncthreads();
  float acc = bi[j];
#pragma unroll
  for (int k = 0; k < 16; ++k) acc += xs[k] * Wi[k * 256 + j];
  h[(size_t)i * 256 + j] = acc;
}

// ---------------- MFMA bf16 GEMM: C = act(A[M,K]_f32 @ B + bias), Bt = bf16 [N][K] ----------------
// 64x64 tile, BK=64, 256 threads (4 waves as 2x2 of 32x32), M%64==0, K%64==0, N arbitrary.
template <int ACT>
__global__ __launch_bounds__(256) void gemm_mfma(
    const float* __restrict__ A, const short* __restrict__ Bt,
    const float* __restrict__ bias, float* __restrict__ C,
    int M, int N, int K) {
  __shared__ short As[64 * 64];  // [row][64 k], 16B slots XOR-swizzled by (row&7)
  __shared__ short Bs[64 * 64];  // [col][64 k]

  const int t = threadIdx.x;
  const int bm = blockIdx.y, bn = blockIdx.x;
  const int srow = t >> 2;        // staging row 0..63
  const int spair = t & 3;        // staging slot pair (slots spair*2, spair*2+1)

  const int lane = t & 63, wid = t >> 6;
  const int wr = wid >> 1, wc = wid & 1;
  const int fr = lane & 15, fs = lane >> 4;

  f32x4 acc[2][2];
#pragma unroll
  for (int m = 0; m < 2; ++m)
#pragma unroll
    for (int n = 0; n < 2; ++n) acc[m][n] = (f32x4){0.f, 0.f, 0.f, 0.f};

  const float* ap = A + (size_t)(bm * 64 + srow) * K + spair * 16;
  const int ng = bn * 64 + srow;
  const short* bp = Bt + (size_t)ng * K + spair * 16;

  // A-frag rows / B-frag cols for this lane
  const int ar0 = wr * 32 + fr, ar1 = ar0 + 16;
  const int bc0 = wc * 32 + fr, bc1 = bc0 + 16;

#define SLOT(base, row, slot) ((base) + (row) * 64 + (((slot) ^ ((row) & 7)) * 8))

  for (int k0 = 0; k0 < K; k0 += 64) {
    // ---- stage A (64x64 f32 -> bf16) ----
    float4 f0 = *(const float4*)(ap + k0);
    float4 f1 = *(const float4*)(ap + k0 + 4);
    float4 f2 = *(const float4*)(ap + k0 + 8);
    float4 f3 = *(const float4*)(ap + k0 + 12);
    bf16x8 alo, ahi;
    alo[0] = f2bf(f0.x); alo[1] = f2bf(f0.y); alo[2] = f2bf(f0.z); alo[3] = f2bf(f0.w);
    alo[4] = f2bf(f1.x); alo[5] = f2bf(f1.y); alo[6] = f2bf(f1.z); alo[7] = f2bf(f1.w);
    ahi[0] = f2bf(f2.x); ahi[1] = f2bf(f2.y); ahi[2] = f2bf(f2.z); ahi[3] = f2bf(f2.w);
    ahi[4] = f2bf(f3.x); ahi[5] = f2bf(f3.y); ahi[6] = f2bf(f3.z); ahi[7] = f2bf(f3.w);
    *(bf16x8*)SLOT(As, srow, spair * 2) = alo;
    *(bf16x8*)SLOT(As, srow, spair * 2 + 1) = ahi;
    // ---- stage B (64 rows of Bt, bf16) ----
    bf16x8 blo, bhi;
    if (ng < N) {
      blo = *(const bf16x8*)(bp + k0);
      bhi = *(const bf16x8*)(bp + k0 + 8);
    } else {
      blo = (bf16x8){0, 0, 0, 0, 0, 0, 0, 0};
      bhi = blo;
    }
    *(bf16x8*)SLOT(Bs, srow, spair * 2) = blo;
    *(bf16x8*)SLOT(Bs, srow, spair * 2 + 1) = bhi;
    __syncthreads();

#pragma unroll
    for (int ks = 0; ks < 2; ++ks) {
      const int slot = ks * 4 + fs;
      bf16x8 a0 = *(const bf16x8*)SLOT(As, ar0, slot);
      bf16x8 a1 = *(const bf16x8*)SLOT(As, ar1, slot);
      bf16x8 b0 = *(const bf16x8*)SLOT(Bs, bc0, slot);
      bf16x8 b1 = *(const bf16x8*)SLOT(Bs, bc1, slot);
      acc[0][0] = __builtin_amdgcn_mfma_f32_16x16x32_bf16(a0, b0, acc[0][0], 0, 0, 0);
      acc[0][1] = __builtin_amdgcn_mfma_f32_16x16x32_bf16(a0, b1, acc[0][1], 0, 0, 0);
      acc[1][0] = __builtin_amdgcn_mfma_f32_16x16x32_bf16(a1, b0, acc[1][0], 0, 0, 0);
      acc[1][1] = __builtin_amdgcn_mfma_f32_16x16x32_bf16(a1, b1, acc[1][1], 0, 0, 0);
    }
    __syncthreads();
  }
#undef SLOT

  // ---- epilogue: C row = fs*4+j, col = fr (per m89 C/D layout) ----
#pragma unroll
  for (int n = 0; n < 2; ++n) {
    const int col = bn * 64 + wc * 32 + n * 16 + fr;
    if (col >= N) continue;
    const float bv = bias[col];
#pragma unroll
    for (int m = 0; m < 2; ++m) {
      const int rbase = bm * 64 + wr * 32 + m * 16 + fs * 4;
#pragma unroll
      for (int j = 0; j < 4; ++j) {
        float v = acc[m][n][j] + bv;
        if (ACT == 1) v = fmaxf(v, 0.f);
        C[(size_t)(rbase + j) * N + col] = v;
      }
    }
  }
}

// ---------------- block-diagonal flash attention ----------------
__global__ __launch_bounds__(64) void attn_kernel(
    const float* __restrict__ qkv, const int* __restrict__ starts,
    const int* __restrict__ batch, float* __restrict__ out) {
  __shared__ float red[64][32];
  const int i = blockIdx.x >> 3;
  const int h = blockIdx.x & 7;
  const int lane = threadIdx.x;
  const int g = batch[i];
  const int js = starts[g], je = starts[g + 1];

  const float* qp = qkv + (size_t)i * 768 + h * 32;
  float q[32];
#pragma unroll
  for (int d4 = 0; d4 < 8; ++d4) {
    float4 v = *(const float4*)(qp + d4 * 4);
    q[d4 * 4 + 0] = v.x; q[d4 * 4 + 1] = v.y; q[d4 * 4 + 2] = v.z; q[d4 * 4 + 3] = v.w;
  }

  float m = NEG_INF, lsum = 0.f;
  float acc[32];
#pragma unroll
  for (int d = 0; d < 32; ++d) acc[d] = 0.f;
  const float scale = 0.17677669529663687f;

  for (int j = js + lane; j < je; j += 64) {
    const float* kp = qkv + (size_t)j * 768 + 256 + h * 32;
    float s = 0.f;
#pragma unroll
    for (int d4 = 0; d4 < 8; ++d4) {
      float4 kv = *(const float4*)(kp + d4 * 4);
      s += q[d4 * 4 + 0] * kv.x + q[d4 * 4 + 1] * kv.y +
           q[d4 * 4 + 2] * kv.z + q[d4 * 4 + 3] * kv.w;
    }
    s *= scale;
    float mo = m;
    m = fmaxf(m, s);
    float corr = __expf(mo - m);
    float p = __expf(s - m);
    lsum = lsum * corr + p;
    const float* vp = kp + 256;
#pragma unroll
    for (int d4 = 0; d4 < 8; ++d4) {
      float4 vv = *(const float4*)(vp + d4 * 4);
      acc[d4 * 4 + 0] = acc[d4 * 4 + 0] * corr + p * vv.x;
      acc[d4 * 4 + 1] = acc[d4 * 4 + 1] * corr + p * vv.y;
      acc[d4 * 4 + 2] = acc[d4 * 4 + 2] * corr + p * vv.z;
      acc[d4 * 4 + 3] = acc[d4 * 4 + 3] * corr + p * vv.w;
    }
  }

  float mw = wave_max64(m);
  float corr = (m == NEG_INF) ? 0.f : __expf(m - mw);
  lsum *= corr;
  lsum = wave_sum64(lsum);
#pragma unroll
  for (int d = 0; d < 32; ++d) red[lane][d] = acc[d] * corr;
  __syncthreads();
  if (lane < 32) {
    float s = 0.f;
#pragma unroll
    for (int l = 0; l < 64; ++l) s += red[l][lane];
    out[(size_t)i * 256 + h * 32 + lane] = s / lsum;
  }
}

// ---------------- fused residual + LayerNorm (D=256) ----------------
__global__ __launch_bounds__(256) void ln_kernel(
    const float* __restrict__ base, const float* __restrict__ delta,
    const float* __restrict__ s, const float* __restrict__ b,
    float* __restrict__ out) {
  const int row = blockIdx.x * 4 + (threadIdx.x >> 6);
  const int lane = threadIdx.x & 63;
  const float4 xa = *(const float4*)(base + (size_t)row * 256 + lane * 4);
  const float4 xb = *(const float4*)(delta + (size_t)row * 256 + lane * 4);
  float4 v = make_float4(xa.x + xb.x, xa.y + xb.y, xa.z + xb.z, xa.w + xb.w);
  float sum = v.x + v.y + v.z + v.w;
  sum = wave_sum64(sum);
  const float mean = sum * (1.f / 256.f);
  float4 d = make_float4(v.x - mean, v.y - mean, v.z - mean, v.w - mean);
  float sq = d.x * d.x + d.y * d.y + d.z * d.z + d.w * d.w;
  sq = wave_sum64(sq);
  const float rs = rsqrtf(sq * (1.f / 256.f) + 1e-5f);
  const float4 sv = *(const float4*)(s + lane * 4);
  const float4 bv = *(const float4*)(b + lane * 4);
  float4 o = make_float4(d.x * rs * sv.x + bv.x, d.y * rs * sv.y + bv.y,
                         d.z * rs * sv.z + bv.z, d.w * rs * sv.w + bv.w);
  *(float4*)(out + (size_t)row * 256 + lane * 4) = o;
}

// ---------------- lat normalization ----------------
__global__ __launch_bounds__(256) void latnorm_kernel(float* __restrict__ lat) {
  const int idx = blockIdx.x * 256 + threadIdx.x;
  const int row = idx >> 5;
  const int c = idx & 31;
  float v = lat[(size_t)row * 32 + c];
  float sq = v * v;
#pragma unroll
  for (int m = 16; m >= 1; m >>= 1) sq += __shfl_xor(sq, m, 32);
  const float norm = fmaxf(sqrtf(sq), 1e-12f);
  lat[(size_t)row * 32 + c] = v / norm * 5.656854249492381f;
}

// ---------------- beta head ----------------
__global__ __launch_bounds__(256) void beta_kernel(
    const float* __restrict__ bh, const float* __restrict__ w,
    const float* __restrict__ b2b, float* __restrict__ beta) {
  const int row = blockIdx.x * 4 + (threadIdx.x >> 6);
  const int lane = threadIdx.x & 63;
  float p = bh[(size_t)row * 128 + lane] * w[lane] +
            bh[(size_t)row * 128 + 64 + lane] * w[64 + lane];
  p = wave_sum64(p);
  if (lane == 0) {
    float x = p + b2b[0];
    float sgm = 1.f / (1.f + __expf(-x));
    sgm = fminf(fmaxf(sgm, 1e-6f), 1.f - 1e-6f);
    beta[row] = sgm;
  }
}

// ---------------- launch ----------------
extern "C" void kernel_launch(void* const* d_in, const int* in_sizes, int n_in,
                              void* d_out, int out_size, void* d_ws, size_t ws_size,
                              hipStream_t stream) {
  const int N = 2048, G = 16, D = 256, FF = 1024, L = 4;

  const float* x     = (const float*)d_in[0];
  const int*   batch = (const int*)d_in[2];
  const float* Wi    = (const float*)d_in[3];
  const float* bi    = (const float*)d_in[4];
  const float* qkv_w = (const float*)d_in[5];
  const float* qkv_b = (const float*)d_in[6];
  const float* out_w = (const float*)d_in[7];
  const float* out_b = (const float*)d_in[8];
  const float* ff1_w = (const float*)d_in[9];
  const float* ff1_b = (const float*)d_in[10];
  const float* ff2_w = (const float*)d_in[11];
  const float* ff2_b = (const float*)d_in[12];
  const float* ln1_s = (const float*)d_in[13];
  const float* ln1_b = (const float*)d_in[14];
  const float* ln2_s = (const float*)d_in[15];
  const float* ln2_b = (const float*)d_in[16];
  const float* lat_w = (const float*)d_in[17];
  const float* lat_b = (const float*)d_in[18];
  const float* b1_w  = (const float*)d_in[19];
  const float* b1_b  = (const float*)d_in[20];
  const float* b2_w  = (const float*)d_in[21];
  const float* b2_b  = (const float*)d_in[22];

  float* ws = (float*)d_ws;
  float* h       = ws;                       // N*D
  float* qkv     = h + (size_t)N * D;        // N*3D
  float* attnout = qkv + (size_t)N * 3 * D;  // N*D
  float* tmp     = attnout + (size_t)N * D;  // N*D
  float* ffbuf   = tmp + (size_t)N * D;      // N*FF
  float* bh      = ffbuf + (size_t)N * FF;   // N*128
  int*   starts  = (int*)(bh + (size_t)N * 128);  // G+1 (pad 32)
  short* wb      = (short*)(starts + 32);
  short* qkv_t = wb;                              // L*768*256
  short* out_t = qkv_t + (size_t)L * 768 * 256;   // L*256*256
  short* ff1_t = out_t + (size_t)L * 256 * 256;   // L*1024*256
  short* ff2_t = ff1_t + (size_t)L * 1024 * 256;  // L*256*1024
  short* b1_t  = ff2_t + (size_t)L * 256 * 1024;  // 128*256
  short* lat_t = b1_t + (size_t)128 * 256;        // 32*256

  float* beta_out = (float*)d_out;
  float* lat_out  = beta_out + N;

  pack_weights<<<3112, 256, 0, stream>>>(qkv_w, out_w, ff1_w, ff2_w, b1_w, lat_w,
                                         qkv_t, out_t, ff1_t, ff2_t, b1_t, lat_t);
  starts_kernel<<<(N + 255) / 256, 256, 0, stream>>>(batch, starts, N, G);
  inproj_kernel<<<N, 256, 0, stream>>>(x, Wi, bi, h);

  for (int l = 0; l < L; ++l) {
    gemm_mfma<0><<<dim3(768 / 64, N / 64), 256, 0, stream>>>(
        h, qkv_t + (size_t)l * 768 * 256, qkv_b + (size_t)l * 768, qkv, N, 768, 256);
    attn_kernel<<<N * 8, 64, 0, stream>>>(qkv, starts, batch, attnout);
    gemm_mfma<0><<<dim3(256 / 64, N / 64), 256, 0, stream>>>(
        attnout, out_t + (size_t)l * 256 * 256, out_b + (size_t)l * 256, tmp, N, 256, 256);
    ln_kernel<<<N / 4, 256, 0, stream>>>(h, tmp, ln1_s + (size_t)l * D, ln1_b + (size_t)l * D, h);
    gemm_mfma<1><<<dim3(FF / 64, N / 64), 256, 0, stream>>>(
        h, ff1_t + (size_t)l * FF * 256, ff1_b + (size_t)l * FF, ffbuf, N, FF, 256);
    gemm_mfma<0><<<dim3(256 / 64, N / 64), 256, 0, stream>>>(
        ffbuf, ff2_t + (size_t)l * 256 * FF, ff2_b + (size_t)l * 256, tmp, N, 256, FF);
    ln_kernel<<<N / 4, 256, 0, stream>>>(h, tmp, ln2_s + (size_t)l * D, ln2_b + (size_t)l * D, h);
  }

  gemm_mfma<0><<<dim3(1, N / 64), 256, 0, stream>>>(h, lat_t, lat_b, lat_out, N, 32, 256);
  latnorm_kernel<<<(N * 32) / 256, 256, 0, stream>>>(lat_out);

  gemm_mfma<1><<<dim3(2, N / 64), 256, 0, stream>>>(h, b1_t, b1_b, bh, N, 128, 256);
  beta_kernel<<<N / 4, 256, 0, stream>>>(bh, b2_w, b2_b, beta_out);
}

// Round 3
// 384.556 us; speedup vs baseline: 2.4228x; 1.3164x over previous
//
#include <hip/hip_runtime.h>
#include <hip/hip_bf16.h>

#define NEG_INF (-__builtin_inff())

typedef __attribute__((ext_vector_type(8))) short bf16x8;
typedef __attribute__((ext_vector_type(4))) float f32x4;

// ---------------- helpers ----------------
__device__ inline float wave_sum64(float v) {
#pragma unroll
  for (int m = 32; m >= 1; m >>= 1) v += __shfl_xor(v, m, 64);
  return v;
}
__device__ inline ushort f2bf(float f) {  // RNE float->bf16
  uint u = __float_as_uint(f);
  return (ushort)((u + 0x7FFFu + ((u >> 16) & 1u)) >> 16);
}

// ---------------- graph boundary kernel ----------------
__global__ void starts_kernel(const int* __restrict__ batch, int* __restrict__ starts,
                              int N, int G) {
  int i = blockIdx.x * blockDim.x + threadIdx.x;
  if (i >= N) return;
  int b = batch[i];
  if (i == 0) {
    for (int g = 0; g <= b; ++g) starts[g] = 0;
  } else {
    int bp = batch[i - 1];
    for (int g = bp + 1; g <= b; ++g) starts[g] = i;
  }
  if (i == N - 1) {
    for (int g = b + 1; g <= G; ++g) starts[g] = N;
  }
}

// ---------------- weight pack: f32 [K][N] -> bf16 [N][K] (B^T), all weights ----------------
__global__ __launch_bounds__(256) void pack_weights(
    const float* __restrict__ qkv_w, const float* __restrict__ out_w,
    const float* __restrict__ ff1_w, const float* __restrict__ ff2_w,
    const float* __restrict__ b1_w, const float* __restrict__ lat_w,
    short* __restrict__ qkv_t, short* __restrict__ out_t,
    short* __restrict__ ff1_t, short* __restrict__ ff2_t,
    short* __restrict__ b1_t, short* __restrict__ lat_t) {
  int t = blockIdx.x;
  const float* src;
  short* dst;
  int Kd, Nd, rem;
  if (t < 768) {
    int l = t / 192; rem = t % 192; Kd = 256; Nd = 768;
    src = qkv_w + (size_t)l * Kd * Nd; dst = qkv_t + (size_t)l * Nd * Kd;
  } else if (t < 1024) {
    t -= 768; int l = t / 64; rem = t % 64; Kd = 256; Nd = 256;
    src = out_w + (size_t)l * Kd * Nd; dst = out_t + (size_t)l * Nd * Kd;
  } else if (t < 2048) {
    t -= 1024; int l = t / 256; rem = t % 256; Kd = 256; Nd = 1024;
    src = ff1_w + (size_t)l * Kd * Nd; dst = ff1_t + (size_t)l * Nd * Kd;
  } else if (t < 3072) {
    t -= 2048; int l = t / 256; rem = t % 256; Kd = 1024; Nd = 256;
    src = ff2_w + (size_t)l * Kd * Nd; dst = ff2_t + (size_t)l * Nd * Kd;
  } else if (t < 3104) {
    rem = t - 3072; Kd = 256; Nd = 128; src = b1_w; dst = b1_t;
  } else {
    rem = t - 3104; Kd = 256; Nd = 32; src = lat_w; dst = lat_t;
  }
  const int ntn = Nd / 32;
  const int kt = rem / ntn, nt = rem % ntn;

  __shared__ float tile[32][33];
  const int tx = threadIdx.x & 31, ty = threadIdx.x >> 5;
#pragma unroll
  for (int r = 0; r < 4; ++r) {
    int k = kt * 32 + ty + r * 8;
    tile[ty + r * 8][tx] = src[(size_t)k * Nd + nt * 32 + tx];
  }
  __syncthreads();
#pragma unroll
  for (int r = 0; r < 4; ++r) {
    int n = nt * 32 + ty + r * 8;
    dst[(size_t)n * Kd + kt * 32 + tx] = (short)f2bf(tile[tx][ty + r * 8]);
  }
}

// ---------------- input projection: h = x @ Wi + bi  (K=16, D=256) ----------------
__global__ __launch_bounds__(256) void inproj_kernel(
    const float* __restrict__ x, const float* __restrict__ Wi,
    const float* __restrict__ bi, float* __restrict__ h) {
  __shared__ float xs[16];
  const int i = blockIdx.x, j = threadIdx.x;
  if (j < 16) xs[j] = x[(size_t)i * 16 + j];
  __syncthreads();
  float acc = bi[j];
#pragma unroll
  for (int k = 0; k < 16; ++k) acc += xs[k] * Wi[k * 256 + j];
  h[(size_t)i * 256 + j] = acc;
}

// ---------------- MFMA bf16 GEMM: C = act(A[M,K]_f32 @ B + bias), Bt = bf16 [N][K] ----------------
template <int ACT>
__global__ __launch_bounds__(256) void gemm_mfma(
    const float* __restrict__ A, const short* __restrict__ Bt,
    const float* __restrict__ bias, float* __restrict__ C,
    int M, int N, int K) {
  __shared__ short As[64 * 64];
  __shared__ short Bs[64 * 64];

  const int t = threadIdx.x;
  const int bm = blockIdx.y, bn = blockIdx.x;
  const int srow = t >> 2;
  const int spair = t & 3;

  const int lane = t & 63, wid = t >> 6;
  const int wr = wid >> 1, wc = wid & 1;
  const int fr = lane & 15, fs = lane >> 4;

  f32x4 acc[2][2];
#pragma unroll
  for (int m = 0; m < 2; ++m)
#pragma unroll
    for (int n = 0; n < 2; ++n) acc[m][n] = (f32x4){0.f, 0.f, 0.f, 0.f};

  const float* ap = A + (size_t)(bm * 64 + srow) * K + spair * 16;
  const int ng = bn * 64 + srow;
  const short* bp = Bt + (size_t)ng * K + spair * 16;

  const int ar0 = wr * 32 + fr, ar1 = ar0 + 16;
  const int bc0 = wc * 32 + fr, bc1 = bc0 + 16;

#define SLOT(base, row, slot) ((base) + (row) * 64 + (((slot) ^ ((row) & 7)) * 8))

  for (int k0 = 0; k0 < K; k0 += 64) {
    float4 f0 = *(const float4*)(ap + k0);
    float4 f1 = *(const float4*)(ap + k0 + 4);
    float4 f2 = *(const float4*)(ap + k0 + 8);
    float4 f3 = *(const float4*)(ap + k0 + 12);
    bf16x8 alo, ahi;
    alo[0] = f2bf(f0.x); alo[1] = f2bf(f0.y); alo[2] = f2bf(f0.z); alo[3] = f2bf(f0.w);
    alo[4] = f2bf(f1.x); alo[5] = f2bf(f1.y); alo[6] = f2bf(f1.z); alo[7] = f2bf(f1.w);
    ahi[0] = f2bf(f2.x); ahi[1] = f2bf(f2.y); ahi[2] = f2bf(f2.z); ahi[3] = f2bf(f2.w);
    ahi[4] = f2bf(f3.x); ahi[5] = f2bf(f3.y); ahi[6] = f2bf(f3.z); ahi[7] = f2bf(f3.w);
    *(bf16x8*)SLOT(As, srow, spair * 2) = alo;
    *(bf16x8*)SLOT(As, srow, spair * 2 + 1) = ahi;
    bf16x8 blo, bhi;
    if (ng < N) {
      blo = *(const bf16x8*)(bp + k0);
      bhi = *(const bf16x8*)(bp + k0 + 8);
    } else {
      blo = (bf16x8){0, 0, 0, 0, 0, 0, 0, 0};
      bhi = blo;
    }
    *(bf16x8*)SLOT(Bs, srow, spair * 2) = blo;
    *(bf16x8*)SLOT(Bs, srow, spair * 2 + 1) = bhi;
    __syncthreads();

#pragma unroll
    for (int ks = 0; ks < 2; ++ks) {
      const int slot = ks * 4 + fs;
      bf16x8 a0 = *(const bf16x8*)SLOT(As, ar0, slot);
      bf16x8 a1 = *(const bf16x8*)SLOT(As, ar1, slot);
      bf16x8 b0 = *(const bf16x8*)SLOT(Bs, bc0, slot);
      bf16x8 b1 = *(const bf16x8*)SLOT(Bs, bc1, slot);
      acc[0][0] = __builtin_amdgcn_mfma_f32_16x16x32_bf16(a0, b0, acc[0][0], 0, 0, 0);
      acc[0][1] = __builtin_amdgcn_mfma_f32_16x16x32_bf16(a0, b1, acc[0][1], 0, 0, 0);
      acc[1][0] = __builtin_amdgcn_mfma_f32_16x16x32_bf16(a1, b0, acc[1][0], 0, 0, 0);
      acc[1][1] = __builtin_amdgcn_mfma_f32_16x16x32_bf16(a1, b1, acc[1][1], 0, 0, 0);
    }
    __syncthreads();
  }
#undef SLOT

#pragma unroll
  for (int n = 0; n < 2; ++n) {
    const int col = bn * 64 + wc * 32 + n * 16 + fr;
    if (col >= N) continue;
    const float bv = bias[col];
#pragma unroll
    for (int m = 0; m < 2; ++m) {
      const int rbase = bm * 64 + wr * 32 + m * 16 + fs * 4;
#pragma unroll
      for (int j = 0; j < 4; ++j) {
        float v = acc[m][n][j] + bv;
        if (ACT == 1) v = fmaxf(v, 0.f);
        C[(size_t)(rbase + j) * N + col] = v;
      }
    }
  }
}

// ---------------- block-diagonal attention, coalesced lane-over-dims layout ----------------
// One wave per node i; lane l owns dims 4l..4l+3 (head = l>>3). K/V row loads are
// coalesced float4 (1 txn/wave). Per-head dot via 3-step shfl_xor in the 8-lane group.
// 4-deep register prefetch queue hides L2 latency over the serial j-loop. No LDS.
__global__ __launch_bounds__(256) void attn_kernel(
    const float* __restrict__ qkv, const int* __restrict__ starts,
    const int* __restrict__ batch, float* __restrict__ out) {
  const int i = blockIdx.x * 4 + (threadIdx.x >> 6);
  const int lane = threadIdx.x & 63;
  const int g = batch[i];
  const int js = starts[g], je = starts[g + 1];
  const float4 f4z = make_float4(0.f, 0.f, 0.f, 0.f);

  float4 q = *(const float4*)(qkv + (size_t)i * 768 + lane * 4);
  const float scale = 0.17677669529663687f;  // 1/sqrt(32)
  q.x *= scale; q.y *= scale; q.z *= scale; q.w *= scale;

  const float* kb = qkv + 256 + lane * 4;
  const float* vb = qkv + 512 + lane * 4;

  float m = NEG_INF, lsum = 0.f;
  float4 acc = f4z;

  float4 kq[4], vq[4];
#pragma unroll
  for (int t = 0; t < 4; ++t) {
    kq[t] = (js + t < je) ? *(const float4*)(kb + (size_t)(js + t) * 768) : f4z;
    vq[t] = (js + t < je) ? *(const float4*)(vb + (size_t)(js + t) * 768) : f4z;
  }

  for (int j = js; j < je; j += 4) {
    float4 ck[4], cv[4];
#pragma unroll
    for (int t = 0; t < 4; ++t) { ck[t] = kq[t]; cv[t] = vq[t]; }
#pragma unroll
    for (int t = 0; t < 4; ++t) {
      const int jn = j + 4 + t;
      kq[t] = (jn < je) ? *(const float4*)(kb + (size_t)jn * 768) : f4z;
      vq[t] = (jn < je) ? *(const float4*)(vb + (size_t)jn * 768) : f4z;
    }
#pragma unroll
    for (int t = 0; t < 4; ++t) {
      if (j + t < je) {
        float s = q.x * ck[t].x + q.y * ck[t].y + q.z * ck[t].z + q.w * ck[t].w;
        s += __shfl_xor(s, 1, 64);
        s += __shfl_xor(s, 2, 64);
        s += __shfl_xor(s, 4, 64);
        if (s > m) {  // online-softmax rescale only when max grows
          const float corr = __expf(m - s);  // exp(-inf)=0 on first hit
          lsum *= corr;
          acc.x *= corr; acc.y *= corr; acc.z *= corr; acc.w *= corr;
          m = s;
        }
        const float p = __expf(s - m);
        lsum += p;
        acc.x += p * cv[t].x; acc.y += p * cv[t].y;
        acc.z += p * cv[t].z; acc.w += p * cv[t].w;
      }
    }
  }

  const float inv = 1.f / lsum;
  float4 o = make_float4(acc.x * inv, acc.y * inv, acc.z * inv, acc.w * inv);
  *(float4*)(out + (size_t)i * 256 + lane * 4) = o;
}

// ---------------- fused residual + LayerNorm (D=256) ----------------
__global__ __launch_bounds__(256) void ln_kernel(
    const float* __restrict__ base, const float* __restrict__ delta,
    const float* __restrict__ s, const float* __restrict__ b,
    float* __restrict__ out) {
  const int row = blockIdx.x * 4 + (threadIdx.x >> 6);
  const int lane = threadIdx.x & 63;
  const float4 xa = *(const float4*)(base + (size_t)row * 256 + lane * 4);
  const float4 xb = *(const float4*)(delta + (size_t)row * 256 + lane * 4);
  float4 v = make_float4(xa.x + xb.x, xa.y + xb.y, xa.z + xb.z, xa.w + xb.w);
  float sum = v.x + v.y + v.z + v.w;
  sum = wave_sum64(sum);
  const float mean = sum * (1.f / 256.f);
  float4 d = make_float4(v.x - mean, v.y - mean, v.z - mean, v.w - mean);
  float sq = d.x * d.x + d.y * d.y + d.z * d.z + d.w * d.w;
  sq = wave_sum64(sq);
  const float rs = rsqrtf(sq * (1.f / 256.f) + 1e-5f);
  const float4 sv = *(const float4*)(s + lane * 4);
  const float4 bv = *(const float4*)(b + lane * 4);
  float4 o = make_float4(d.x * rs * sv.x + bv.x, d.y * rs * sv.y + bv.y,
                         d.z * rs * sv.z + bv.z, d.w * rs * sv.w + bv.w);
  *(float4*)(out + (size_t)row * 256 + lane * 4) = o;
}

// ---------------- lat normalization ----------------
__global__ __launch_bounds__(256) void latnorm_kernel(float* __restrict__ lat) {
  const int idx = blockIdx.x * 256 + threadIdx.x;
  const int row = idx >> 5;
  const int c = idx & 31;
  float v = lat[(size_t)row * 32 + c];
  float sq = v * v;
#pragma unroll
  for (int m = 16; m >= 1; m >>= 1) sq += __shfl_xor(sq, m, 32);
  const float norm = fmaxf(sqrtf(sq), 1e-12f);
  lat[(size_t)row * 32 + c] = v / norm * 5.656854249492381f;
}

// ---------------- beta head ----------------
__global__ __launch_bounds__(256) void beta_kernel(
    const float* __restrict__ bh, const float* __restrict__ w,
    const float* __restrict__ b2b, float* __restrict__ beta) {
  const int row = blockIdx.x * 4 + (threadIdx.x >> 6);
  const int lane = threadIdx.x & 63;
  float p = bh[(size_t)row * 128 + lane] * w[lane] +
            bh[(size_t)row * 128 + 64 + lane] * w[64 + lane];
  p = wave_sum64(p);
  if (lane == 0) {
    float x = p + b2b[0];
    float sgm = 1.f / (1.f + __expf(-x));
    sgm = fminf(fmaxf(sgm, 1e-6f), 1.f - 1e-6f);
    beta[row] = sgm;
  }
}

// ---------------- launch ----------------
extern "C" void kernel_launch(void* const* d_in, const int* in_sizes, int n_in,
                              void* d_out, int out_size, void* d_ws, size_t ws_size,
                              hipStream_t stream) {
  const int N = 2048, G = 16, D = 256, FF = 1024, L = 4;

  const float* x     = (const float*)d_in[0];
  const int*   batch = (const int*)d_in[2];
  const float* Wi    = (const float*)d_in[3];
  const float* bi    = (const float*)d_in[4];
  const float* qkv_w = (const float*)d_in[5];
  const float* qkv_b = (const float*)d_in[6];
  const float* out_w = (const float*)d_in[7];
  const float* out_b = (const float*)d_in[8];
  const float* ff1_w = (const float*)d_in[9];
  const float* ff1_b = (const float*)d_in[10];
  const float* ff2_w = (const float*)d_in[11];
  const float* ff2_b = (const float*)d_in[12];
  const float* ln1_s = (const float*)d_in[13];
  const float* ln1_b = (const float*)d_in[14];
  const float* ln2_s = (const float*)d_in[15];
  const float* ln2_b = (const float*)d_in[16];
  const float* lat_w = (const float*)d_in[17];
  const float* lat_b = (const float*)d_in[18];
  const float* b1_w  = (const float*)d_in[19];
  const float* b1_b  = (const float*)d_in[20];
  const float* b2_w  = (const float*)d_in[21];
  const float* b2_b  = (const float*)d_in[22];

  float* ws = (float*)d_ws;
  float* h       = ws;                       // N*D
  float* qkv     = h + (size_t)N * D;        // N*3D
  float* attnout = qkv + (size_t)N * 3 * D;  // N*D
  float* tmp     = attnout + (size_t)N * D;  // N*D
  float* ffbuf   = tmp + (size_t)N * D;      // N*FF
  float* bh      = ffbuf + (size_t)N * FF;   // N*128
  int*   starts  = (int*)(bh + (size_t)N * 128);  // G+1 (pad 32)
  short* wb      = (short*)(starts + 32);
  short* qkv_t = wb;                              // L*768*256
  short* out_t = qkv_t + (size_t)L * 768 * 256;   // L*256*256
  short* ff1_t = out_t + (size_t)L * 256 * 256;   // L*1024*256
  short* ff2_t = ff1_t + (size_t)L * 1024 * 256;  // L*256*1024
  short* b1_t  = ff2_t + (size_t)L * 256 * 1024;  // 128*256
  short* lat_t = b1_t + (size_t)128 * 256;        // 32*256

  float* beta_out = (float*)d_out;
  float* lat_out  = beta_out + N;

  pack_weights<<<3112, 256, 0, stream>>>(qkv_w, out_w, ff1_w, ff2_w, b1_w, lat_w,
                                         qkv_t, out_t, ff1_t, ff2_t, b1_t, lat_t);
  starts_kernel<<<(N + 255) / 256, 256, 0, stream>>>(batch, starts, N, G);
  inproj_kernel<<<N, 256, 0, stream>>>(x, Wi, bi, h);

  for (int l = 0; l < L; ++l) {
    gemm_mfma<0><<<dim3(768 / 64, N / 64), 256, 0, stream>>>(
        h, qkv_t + (size_t)l * 768 * 256, qkv_b + (size_t)l * 768, qkv, N, 768, 256);
    attn_kernel<<<N / 4, 256, 0, stream>>>(qkv, starts, batch, attnout);
    gemm_mfma<0><<<dim3(256 / 64, N / 64), 256, 0, stream>>>(
        attnout, out_t + (size_t)l * 256 * 256, out_b + (size_t)l * 256, tmp, N, 256, 256);
    ln_kernel<<<N / 4, 256, 0, stream>>>(h, tmp, ln1_s + (size_t)l * D, ln1_b + (size_t)l * D, h);
    gemm_mfma<1><<<dim3(FF / 64, N / 64), 256, 0, stream>>>(
        h, ff1_t + (size_t)l * FF * 256, ff1_b + (size_t)l * FF, ffbuf, N, FF, 256);
    gemm_mfma<0><<<dim3(256 / 64, N / 64), 256, 0, stream>>>(
        ffbuf, ff2_t + (size_t)l * 256 * FF, ff2_b + (size_t)l * 256, tmp, N, 256, FF);
    ln_kernel<<<N / 4, 256, 0, stream>>>(h, tmp, ln2_s + (size_t)l * D, ln2_b + (size_t)l * D, h);
  }

  gemm_mfma<0><<<dim3(1, N / 64), 256, 0, stream>>>(h, lat_t, lat_b, lat_out, N, 32, 256);
  latnorm_kernel<<<(N * 32) / 256, 256, 0, stream>>>(lat_out);

  gemm_mfma<1><<<dim3(2, N / 64), 256, 0, stream>>>(h, b1_t, b1_b, bh, N, 128, 256);
  beta_kernel<<<N / 4, 256, 0, stream>>>(bh, b2_w, b2_b, beta_out);
}

// Round 4
// 378.641 us; speedup vs baseline: 2.4606x; 1.0156x over previous
//
#include <hip/hip_runtime.h>
#include <hip/hip_bf16.h>

#define NEG_INF (-__builtin_inff())

typedef __attribute__((ext_vector_type(8))) short bf16x8;
typedef __attribute__((ext_vector_type(4))) float f32x4;

// ---------------- helpers ----------------
__device__ inline float wave_sum64(float v) {
#pragma unroll
  for (int m = 32; m >= 1; m >>= 1) v += __shfl_xor(v, m, 64);
  return v;
}
__device__ inline ushort f2bf(float f) {  // RNE float->bf16
  uint u = __float_as_uint(f);
  return (ushort)((u + 0x7FFFu + ((u >> 16) & 1u)) >> 16);
}

// ---------------- graph boundary kernel ----------------
__global__ void starts_kernel(const int* __restrict__ batch, int* __restrict__ starts,
                              int N, int G) {
  int i = blockIdx.x * blockDim.x + threadIdx.x;
  if (i >= N) return;
  int b = batch[i];
  if (i == 0) {
    for (int g = 0; g <= b; ++g) starts[g] = 0;
  } else {
    int bp = batch[i - 1];
    for (int g = bp + 1; g <= b; ++g) starts[g] = i;
  }
  if (i == N - 1) {
    for (int g = b + 1; g <= G; ++g) starts[g] = N;
  }
}

// ---------------- weight pack: f32 [K][N] -> bf16 [N][K] (B^T), all weights ----------------
__global__ __launch_bounds__(256) void pack_weights(
    const float* __restrict__ qkv_w, const float* __restrict__ out_w,
    const float* __restrict__ ff1_w, const float* __restrict__ ff2_w,
    const float* __restrict__ b1_w, const float* __restrict__ lat_w,
    short* __restrict__ qkv_t, short* __restrict__ out_t,
    short* __restrict__ ff1_t, short* __restrict__ ff2_t,
    short* __restrict__ b1_t, short* __restrict__ lat_t) {
  int t = blockIdx.x;
  const float* src;
  short* dst;
  int Kd, Nd, rem;
  if (t < 768) {
    int l = t / 192; rem = t % 192; Kd = 256; Nd = 768;
    src = qkv_w + (size_t)l * Kd * Nd; dst = qkv_t + (size_t)l * Nd * Kd;
  } else if (t < 1024) {
    t -= 768; int l = t / 64; rem = t % 64; Kd = 256; Nd = 256;
    src = out_w + (size_t)l * Kd * Nd; dst = out_t + (size_t)l * Nd * Kd;
  } else if (t < 2048) {
    t -= 1024; int l = t / 256; rem = t % 256; Kd = 256; Nd = 1024;
    src = ff1_w + (size_t)l * Kd * Nd; dst = ff1_t + (size_t)l * Nd * Kd;
  } else if (t < 3072) {
    t -= 2048; int l = t / 256; rem = t % 256; Kd = 1024; Nd = 256;
    src = ff2_w + (size_t)l * Kd * Nd; dst = ff2_t + (size_t)l * Nd * Kd;
  } else if (t < 3104) {
    rem = t - 3072; Kd = 256; Nd = 128; src = b1_w; dst = b1_t;
  } else {
    rem = t - 3104; Kd = 256; Nd = 32; src = lat_w; dst = lat_t;
  }
  const int ntn = Nd / 32;
  const int kt = rem / ntn, nt = rem % ntn;

  __shared__ float tile[32][33];
  const int tx = threadIdx.x & 31, ty = threadIdx.x >> 5;
#pragma unroll
  for (int r = 0; r < 4; ++r) {
    int k = kt * 32 + ty + r * 8;
    tile[ty + r * 8][tx] = src[(size_t)k * Nd + nt * 32 + tx];
  }
  __syncthreads();
#pragma unroll
  for (int r = 0; r < 4; ++r) {
    int n = nt * 32 + ty + r * 8;
    dst[(size_t)n * Kd + kt * 32 + tx] = (short)f2bf(tile[tx][ty + r * 8]);
  }
}

// ---------------- input projection: h = x @ Wi + bi  (K=16, D=256) ----------------
__global__ __launch_bounds__(256) void inproj_kernel(
    const float* __restrict__ x, const float* __restrict__ Wi,
    const float* __restrict__ bi, float* __restrict__ h) {
  __shared__ float xs[16];
  const int i = blockIdx.x, j = threadIdx.x;
  if (j < 16) xs[j] = x[(size_t)i * 16 + j];
  __syncthreads();
  float acc = bi[j];
#pragma unroll
  for (int k = 0; k < 16; ++k) acc += xs[k] * Wi[k * 256 + j];
  h[(size_t)i * 256 + j] = acc;
}

// ---------------- MFMA bf16 GEMM: C = act(A[M,K]_f32 @ B + bias), Bt = bf16 [N][K] ----------------
template <int ACT>
__global__ __launch_bounds__(256) void gemm_mfma(
    const float* __restrict__ A, const short* __restrict__ Bt,
    const float* __restrict__ bias, float* __restrict__ C,
    int M, int N, int K) {
  __shared__ short As[64 * 64];
  __shared__ short Bs[64 * 64];

  const int t = threadIdx.x;
  const int bm = blockIdx.y, bn = blockIdx.x;
  const int srow = t >> 2;
  const int spair = t & 3;

  const int lane = t & 63, wid = t >> 6;
  const int wr = wid >> 1, wc = wid & 1;
  const int fr = lane & 15, fs = lane >> 4;

  f32x4 acc[2][2];
#pragma unroll
  for (int m = 0; m < 2; ++m)
#pragma unroll
    for (int n = 0; n < 2; ++n) acc[m][n] = (f32x4){0.f, 0.f, 0.f, 0.f};

  const float* ap = A + (size_t)(bm * 64 + srow) * K + spair * 16;
  const int ng = bn * 64 + srow;
  const short* bp = Bt + (size_t)ng * K + spair * 16;

  const int ar0 = wr * 32 + fr, ar1 = ar0 + 16;
  const int bc0 = wc * 32 + fr, bc1 = bc0 + 16;

#define SLOT(base, row, slot) ((base) + (row) * 64 + (((slot) ^ ((row) & 7)) * 8))

  for (int k0 = 0; k0 < K; k0 += 64) {
    float4 f0 = *(const float4*)(ap + k0);
    float4 f1 = *(const float4*)(ap + k0 + 4);
    float4 f2 = *(const float4*)(ap + k0 + 8);
    float4 f3 = *(const float4*)(ap + k0 + 12);
    bf16x8 alo, ahi;
    alo[0] = f2bf(f0.x); alo[1] = f2bf(f0.y); alo[2] = f2bf(f0.z); alo[3] = f2bf(f0.w);
    alo[4] = f2bf(f1.x); alo[5] = f2bf(f1.y); alo[6] = f2bf(f1.z); alo[7] = f2bf(f1.w);
    ahi[0] = f2bf(f2.x); ahi[1] = f2bf(f2.y); ahi[2] = f2bf(f2.z); ahi[3] = f2bf(f2.w);
    ahi[4] = f2bf(f3.x); ahi[5] = f2bf(f3.y); ahi[6] = f2bf(f3.z); ahi[7] = f2bf(f3.w);
    *(bf16x8*)SLOT(As, srow, spair * 2) = alo;
    *(bf16x8*)SLOT(As, srow, spair * 2 + 1) = ahi;
    bf16x8 blo, bhi;
    if (ng < N) {
      blo = *(const bf16x8*)(bp + k0);
      bhi = *(const bf16x8*)(bp + k0 + 8);
    } else {
      blo = (bf16x8){0, 0, 0, 0, 0, 0, 0, 0};
      bhi = blo;
    }
    *(bf16x8*)SLOT(Bs, srow, spair * 2) = blo;
    *(bf16x8*)SLOT(Bs, srow, spair * 2 + 1) = bhi;
    __syncthreads();

#pragma unroll
    for (int ks = 0; ks < 2; ++ks) {
      const int slot = ks * 4 + fs;
      bf16x8 a0 = *(const bf16x8*)SLOT(As, ar0, slot);
      bf16x8 a1 = *(const bf16x8*)SLOT(As, ar1, slot);
      bf16x8 b0 = *(const bf16x8*)SLOT(Bs, bc0, slot);
      bf16x8 b1 = *(const bf16x8*)SLOT(Bs, bc1, slot);
      acc[0][0] = __builtin_amdgcn_mfma_f32_16x16x32_bf16(a0, b0, acc[0][0], 0, 0, 0);
      acc[0][1] = __builtin_amdgcn_mfma_f32_16x16x32_bf16(a0, b1, acc[0][1], 0, 0, 0);
      acc[1][0] = __builtin_amdgcn_mfma_f32_16x16x32_bf16(a1, b0, acc[1][0], 0, 0, 0);
      acc[1][1] = __builtin_amdgcn_mfma_f32_16x16x32_bf16(a1, b1, acc[1][1], 0, 0, 0);
    }
    __syncthreads();
  }
#undef SLOT

#pragma unroll
  for (int n = 0; n < 2; ++n) {
    const int col = bn * 64 + wc * 32 + n * 16 + fr;
    if (col >= N) continue;
    const float bv = bias[col];
#pragma unroll
    for (int m = 0; m < 2; ++m) {
      const int rbase = bm * 64 + wr * 32 + m * 16 + fs * 4;
#pragma unroll
      for (int j = 0; j < 4; ++j) {
        float v = acc[m][n][j] + bv;
        if (ACT == 1) v = fmaxf(v, 0.f);
        C[(size_t)(rbase + j) * N + col] = v;
      }
    }
  }
}

// ---------------- block-diagonal attention, 4 waves per node ----------------
// One block (4 waves) per node i; lane l owns dims 4l..4l+3 (head = l>>3).
// Wave w flash-accumulates over a contiguous quarter of the graph's j-range
// (branchless online softmax), then partials merge via LDS.
__global__ __launch_bounds__(256) void attn_kernel(
    const float* __restrict__ qkv, const int* __restrict__ starts,
    const int* __restrict__ batch, float* __restrict__ out) {
  __shared__ float red[4][64][6];  // [wave][lane][{m,l,ax,ay,az,aw}]
  const int i = blockIdx.x;
  const int lane = threadIdx.x & 63;
  const int w = threadIdx.x >> 6;
  const int g = batch[i];
  const int js = starts[g], je = starts[g + 1];
  const int chunk = ((je - js) + 3) >> 2;
  const int s0 = js + w * chunk;
  const int s1 = min(s0 + chunk, je);
  const float4 f4z = make_float4(0.f, 0.f, 0.f, 0.f);

  float4 q = *(const float4*)(qkv + (size_t)i * 768 + lane * 4);
  const float scale = 0.17677669529663687f;  // 1/sqrt(32)
  q.x *= scale; q.y *= scale; q.z *= scale; q.w *= scale;

  const float* kb = qkv + 256 + lane * 4;
  const float* vb = qkv + 512 + lane * 4;

  float m = NEG_INF, lsum = 0.f;
  float4 acc = f4z;

  float4 kq[4], vq[4];
#pragma unroll
  for (int t = 0; t < 4; ++t) {
    kq[t] = (s0 + t < s1) ? *(const float4*)(kb + (size_t)(s0 + t) * 768) : f4z;
    vq[t] = (s0 + t < s1) ? *(const float4*)(vb + (size_t)(s0 + t) * 768) : f4z;
  }

  for (int j = s0; j < s1; j += 4) {
    float4 ck[4], cv[4];
#pragma unroll
    for (int t = 0; t < 4; ++t) { ck[t] = kq[t]; cv[t] = vq[t]; }
#pragma unroll
    for (int t = 0; t < 4; ++t) {
      const int jn = j + 4 + t;
      kq[t] = (jn < s1) ? *(const float4*)(kb + (size_t)jn * 768) : f4z;
      vq[t] = (jn < s1) ? *(const float4*)(vb + (size_t)jn * 768) : f4z;
    }
#pragma unroll
    for (int t = 0; t < 4; ++t) {
      if (j + t < s1) {
        float s = q.x * ck[t].x + q.y * ck[t].y + q.z * ck[t].z + q.w * ck[t].w;
        s += __shfl_xor(s, 1, 64);
        s += __shfl_xor(s, 2, 64);
        s += __shfl_xor(s, 4, 64);
        const float mn = fmaxf(m, s);
        const float corr = __expf(m - mn);   // exp(-inf)=0 on first hit
        const float p = __expf(s - mn);
        lsum = lsum * corr + p;
        acc.x = acc.x * corr + p * cv[t].x;
        acc.y = acc.y * corr + p * cv[t].y;
        acc.z = acc.z * corr + p * cv[t].z;
        acc.w = acc.w * corr + p * cv[t].w;
        m = mn;
      }
    }
  }

  red[w][lane][0] = m;
  red[w][lane][1] = lsum;
  red[w][lane][2] = acc.x; red[w][lane][3] = acc.y;
  red[w][lane][4] = acc.z; red[w][lane][5] = acc.w;
  __syncthreads();
  if (w == 0) {
    float M = red[0][lane][0];
#pragma unroll
    for (int ww = 1; ww < 4; ++ww) M = fmaxf(M, red[ww][lane][0]);
    float L = 0.f;
    float4 A = f4z;
#pragma unroll
    for (int ww = 0; ww < 4; ++ww) {
      const float c = __expf(red[ww][lane][0] - M);  // exp(-inf)=0 for empty chunks
      L += red[ww][lane][1] * c;
      A.x += red[ww][lane][2] * c; A.y += red[ww][lane][3] * c;
      A.z += red[ww][lane][4] * c; A.w += red[ww][lane][5] * c;
    }
    const float inv = 1.f / L;
    float4 o = make_float4(A.x * inv, A.y * inv, A.z * inv, A.w * inv);
    *(float4*)(out + (size_t)i * 256 + lane * 4) = o;
  }
}

// ---------------- fused residual + LayerNorm (D=256) ----------------
__global__ __launch_bounds__(256) void ln_kernel(
    const float* __restrict__ base, const float* __restrict__ delta,
    const float* __restrict__ s, const float* __restrict__ b,
    float* __restrict__ out) {
  const int row = blockIdx.x * 4 + (threadIdx.x >> 6);
  const int lane = threadIdx.x & 63;
  const float4 xa = *(const float4*)(base + (size_t)row * 256 + lane * 4);
  const float4 xb = *(const float4*)(delta + (size_t)row * 256 + lane * 4);
  float4 v = make_float4(xa.x + xb.x, xa.y + xb.y, xa.z + xb.z, xa.w + xb.w);
  float sum = v.x + v.y + v.z + v.w;
  sum = wave_sum64(sum);
  const float mean = sum * (1.f / 256.f);
  float4 d = make_float4(v.x - mean, v.y - mean, v.z - mean, v.w - mean);
  float sq = d.x * d.x + d.y * d.y + d.z * d.z + d.w * d.w;
  sq = wave_sum64(sq);
  const float rs = rsqrtf(sq * (1.f / 256.f) + 1e-5f);
  const float4 sv = *(const float4*)(s + lane * 4);
  const float4 bv = *(const float4*)(b + lane * 4);
  float4 o = make_float4(d.x * rs * sv.x + bv.x, d.y * rs * sv.y + bv.y,
                         d.z * rs * sv.z + bv.z, d.w * rs * sv.w + bv.w);
  *(float4*)(out + (size_t)row * 256 + lane * 4) = o;
}

// ---------------- lat normalization ----------------
__global__ __launch_bounds__(256) void latnorm_kernel(float* __restrict__ lat) {
  const int idx = blockIdx.x * 256 + threadIdx.x;
  const int row = idx >> 5;
  const int c = idx & 31;
  float v = lat[(size_t)row * 32 + c];
  float sq = v * v;
#pragma unroll
  for (int m = 16; m >= 1; m >>= 1) sq += __shfl_xor(sq, m, 32);
  const float norm = fmaxf(sqrtf(sq), 1e-12f);
  lat[(size_t)row * 32 + c] = v / norm * 5.656854249492381f;
}

// ---------------- beta head ----------------
__global__ __launch_bounds__(256) void beta_kernel(
    const float* __restrict__ bh, const float* __restrict__ w,
    const float* __restrict__ b2b, float* __restrict__ beta) {
  const int row = blockIdx.x * 4 + (threadIdx.x >> 6);
  const int lane = threadIdx.x & 63;
  float p = bh[(size_t)row * 128 + lane] * w[lane] +
            bh[(size_t)row * 128 + 64 + lane] * w[64 + lane];
  p = wave_sum64(p);
  if (lane == 0) {
    float x = p + b2b[0];
    float sgm = 1.f / (1.f + __expf(-x));
    sgm = fminf(fmaxf(sgm, 1e-6f), 1.f - 1e-6f);
    beta[row] = sgm;
  }
}

// ---------------- launch ----------------
extern "C" void kernel_launch(void* const* d_in, const int* in_sizes, int n_in,
                              void* d_out, int out_size, void* d_ws, size_t ws_size,
                              hipStream_t stream) {
  const int N = 2048, G = 16, D = 256, FF = 1024, L = 4;

  const float* x     = (const float*)d_in[0];
  const int*   batch = (const int*)d_in[2];
  const float* Wi    = (const float*)d_in[3];
  const float* bi    = (const float*)d_in[4];
  const float* qkv_w = (const float*)d_in[5];
  const float* qkv_b = (const float*)d_in[6];
  const float* out_w = (const float*)d_in[7];
  const float* out_b = (const float*)d_in[8];
  const float* ff1_w = (const float*)d_in[9];
  const float* ff1_b = (const float*)d_in[10];
  const float* ff2_w = (const float*)d_in[11];
  const float* ff2_b = (const float*)d_in[12];
  const float* ln1_s = (const float*)d_in[13];
  const float* ln1_b = (const float*)d_in[14];
  const float* ln2_s = (const float*)d_in[15];
  const float* ln2_b = (const float*)d_in[16];
  const float* lat_w = (const float*)d_in[17];
  const float* lat_b = (const float*)d_in[18];
  const float* b1_w  = (const float*)d_in[19];
  const float* b1_b  = (const float*)d_in[20];
  const float* b2_w  = (const float*)d_in[21];
  const float* b2_b  = (const float*)d_in[22];

  float* ws = (float*)d_ws;
  float* h       = ws;                       // N*D
  float* qkv     = h + (size_t)N * D;        // N*3D
  float* attnout = qkv + (size_t)N * 3 * D;  // N*D
  float* tmp     = attnout + (size_t)N * D;  // N*D
  float* ffbuf   = tmp + (size_t)N * D;      // N*FF
  float* bh      = ffbuf + (size_t)N * FF;   // N*128
  int*   starts  = (int*)(bh + (size_t)N * 128);  // G+1 (pad 32)
  short* wb      = (short*)(starts + 32);
  short* qkv_t = wb;                              // L*768*256
  short* out_t = qkv_t + (size_t)L * 768 * 256;   // L*256*256
  short* ff1_t = out_t + (size_t)L * 256 * 256;   // L*1024*256
  short* ff2_t = ff1_t + (size_t)L * 1024 * 256;  // L*256*1024
  short* b1_t  = ff2_t + (size_t)L * 256 * 1024;  // 128*256
  short* lat_t = b1_t + (size_t)128 * 256;        // 32*256

  float* beta_out = (float*)d_out;
  float* lat_out  = beta_out + N;

  pack_weights<<<3112, 256, 0, stream>>>(qkv_w, out_w, ff1_w, ff2_w, b1_w, lat_w,
                                         qkv_t, out_t, ff1_t, ff2_t, b1_t, lat_t);
  starts_kernel<<<(N + 255) / 256, 256, 0, stream>>>(batch, starts, N, G);
  inproj_kernel<<<N, 256, 0, stream>>>(x, Wi, bi, h);

  for (int l = 0; l < L; ++l) {
    gemm_mfma<0><<<dim3(768 / 64, N / 64), 256, 0, stream>>>(
        h, qkv_t + (size_t)l * 768 * 256, qkv_b + (size_t)l * 768, qkv, N, 768, 256);
    attn_kernel<<<N, 256, 0, stream>>>(qkv, starts, batch, attnout);
    gemm_mfma<0><<<dim3(256 / 64, N / 64), 256, 0, stream>>>(
        attnout, out_t + (size_t)l * 256 * 256, out_b + (size_t)l * 256, tmp, N, 256, 256);
    ln_kernel<<<N / 4, 256, 0, stream>>>(h, tmp, ln1_s + (size_t)l * D, ln1_b + (size_t)l * D, h);
    gemm_mfma<1><<<dim3(FF / 64, N / 64), 256, 0, stream>>>(
        h, ff1_t + (size_t)l * FF * 256, ff1_b + (size_t)l * FF, ffbuf, N, FF, 256);
    gemm_mfma<0><<<dim3(256 / 64, N / 64), 256, 0, stream>>>(
        ffbuf, ff2_t + (size_t)l * 256 * FF, ff2_b + (size_t)l * 256, tmp, N, 256, FF);
    ln_kernel<<<N / 4, 256, 0, stream>>>(h, tmp, ln2_s + (size_t)l * D, ln2_b + (size_t)l * D, h);
  }

  gemm_mfma<0><<<dim3(1, N / 64), 256, 0, stream>>>(h, lat_t, lat_b, lat_out, N, 32, 256);
  latnorm_kernel<<<(N * 32) / 256, 256, 0, stream>>>(lat_out);

  gemm_mfma<1><<<dim3(2, N / 64), 256, 0, stream>>>(h, b1_t, b1_b, bh, N, 128, 256);
  beta_kernel<<<N / 4, 256, 0, stream>>>(bh, b2_w, b2_b, beta_out);
}